// Round 15
// baseline (552.028 us; speedup 1.0000x reference)
//
#include <hip/hip_runtime.h>
#include <math.h>

// Dims (fixed by the reference)
#define B_   2048
#define C_   64
#define H_   768
#define NC_  1000
#define H2_  384   // H/2
#define H4_  192   // H/4
#define RIN_ 960   // H + H/4

using short8 = __attribute__((ext_vector_type(8))) short;
using f32x4  = __attribute__((ext_vector_type(4))) float;

__device__ __forceinline__ float silu_(float x){
    float e = __expf(-x);
    return x * __fdividef(1.f, 1.f + e);
}
// round-to-nearest-even f32 -> bf16
__device__ __forceinline__ unsigned short f2bf_(float x){
    unsigned int u = __float_as_uint(x);
    u += 0x7fffu + ((u >> 16) & 1u);
    return (unsigned short)(u >> 16);
}
// truncating f32 -> bf16 (lo residuals; residual-of-residual < 2^-17)
__device__ __forceinline__ unsigned short f2bft_(float x){
    return (unsigned short)(__float_as_uint(x) >> 16);
}
__device__ __forceinline__ float bf2f_(unsigned short h){
    return __uint_as_float(((unsigned int)h) << 16);
}

__global__ void k_sentinel(float* __restrict__ out, float code){ out[0] = code; }

// ---------------------------------------------------------------------------
// K1: split w1 rows 0..767 -> chunk-major bf16 hi/lo (the only t1 dependency)
// ---------------------------------------------------------------------------
__global__ __launch_bounds__(256) void k_w1split(const float* __restrict__ w1,
                                                 unsigned short* __restrict__ w1hi,
                                                 unsigned short* __restrict__ w1lo)
{
    const int idx = blockIdx.x * 256 + threadIdx.x;
    const int k = idx / H2_, j = idx - k * H2_;
    float x = w1[idx];
    unsigned short h = f2bf_(x);
    size_t dst = (size_t)(k >> 5) * (H2_ * 32) + (size_t)j * 32 + (k & 31);
    w1hi[dst] = h;
    w1lo[dst] = f2bft_(x - bf2f_(h));
}

// ---------------------------------------------------------------------------
// K2 (combo): blockIdx dispatch over independent work
//   [0,256)     : T1 = te @ w1[:768] + b1 (MFMA bf16x3, 4 waves x 48 cols)
//   [256,544)   : split w2 (384x192) -> chunk-major bf16 hi/lo
//   [544,1544)  : E1[id] = emb[id] @ w1[768:960]
//   [1544]      : int64-vs-int32 detector on ids
// ---------------------------------------------------------------------------
#define CB_T1E_  256
#define CB_W2E_  544
#define CB_E1E_  1544
__global__ __launch_bounds__(256) void k_combo(const float* __restrict__ te,
                                               const float* __restrict__ w1,
                                               const float* __restrict__ w2,
                                               const float* __restrict__ emb,
                                               const int*   __restrict__ ids32,
                                               const unsigned short* __restrict__ w1hi,
                                               const unsigned short* __restrict__ w1lo,
                                               const float* __restrict__ b1,
                                               float* __restrict__ T1,
                                               unsigned short* __restrict__ w2hi,
                                               unsigned short* __restrict__ w2lo,
                                               float* __restrict__ E1,
                                               int* __restrict__ flag)
{
    __shared__ float er[H4_];
    __shared__ int any_nz;
    const int bb = blockIdx.x, t = threadIdx.x;

    if (bb < CB_T1E_) {
        // ---- T1 MFMA: block covers 16 task-rows x 192 cols
        const int bx = bb >> 1, by = bb & 1;
        const int b0 = bx * 16;
        const int jb = by * 192;
        const int w = t >> 6, l = t & 63;
        const int m = l & 15, g = l >> 4;
        const int row = b0 + m;

        f32x4 acc[3];
        #pragma unroll
        for (int jt = 0; jt < 3; ++jt) acc[jt] = (f32x4){0.f, 0.f, 0.f, 0.f};

        for (int ck = 0; ck < 24; ++ck) {
            const int kk = ck * 32;
            const float* pa = te + (size_t)row * H_ + kk + g * 8;
            float4 a0 = *(const float4*)pa;
            float4 a1 = *(const float4*)(pa + 4);
            float av[8] = {a0.x, a0.y, a0.z, a0.w, a1.x, a1.y, a1.z, a1.w};
            short8 ahi, alo;
            #pragma unroll
            for (int i = 0; i < 8; ++i) {
                unsigned short h = f2bf_(av[i]);
                ahi[i] = (short)h;
                alo[i] = (short)f2bft_(av[i] - bf2f_(h));
            }
            #pragma unroll
            for (int jt = 0; jt < 3; ++jt) {
                const int j = jb + w * 48 + jt * 16 + m;
                const size_t o = (size_t)ck * (H2_ * 32) + (size_t)j * 32 + g * 8;
                short8 bhi = *(const short8*)&w1hi[o];
                short8 blo = *(const short8*)&w1lo[o];
                acc[jt] = __builtin_amdgcn_mfma_f32_16x16x32_bf16(ahi, bhi, acc[jt], 0, 0, 0);
                acc[jt] = __builtin_amdgcn_mfma_f32_16x16x32_bf16(ahi, blo, acc[jt], 0, 0, 0);
                acc[jt] = __builtin_amdgcn_mfma_f32_16x16x32_bf16(alo, bhi, acc[jt], 0, 0, 0);
            }
        }
        #pragma unroll
        for (int jt = 0; jt < 3; ++jt) {
            const int j = jb + w * 48 + jt * 16 + m;
            const float bj = b1[j];
            #pragma unroll
            for (int reg = 0; reg < 4; ++reg)
                T1[(size_t)(b0 + g * 4 + reg) * H2_ + j] = acc[jt][reg] + bj;
        }
    } else if (bb < CB_W2E_) {
        const int idx = (bb - CB_T1E_) * 256 + t;      // < 384*192 exactly
        const int k = idx / H4_, j = idx - k * H4_;
        float x = w2[idx];
        unsigned short h = f2bf_(x);
        size_t dst = (size_t)(k >> 5) * (H4_ * 32) + (size_t)j * 32 + (k & 31);
        w2hi[dst] = h;
        w2lo[dst] = f2bft_(x - bf2f_(h));
    } else if (bb < CB_E1E_) {
        const int id = bb - CB_W2E_;
        if (t < H4_) er[t] = emb[id * H4_ + t];
        __syncthreads();
        for (int k = t; k < H2_; k += 256) {
            float acc = 0.f;
            const float* wc = w1 + (size_t)H_ * H2_ + k;
            #pragma unroll 8
            for (int r = 0; r < H4_; ++r) acc += er[r] * wc[(size_t)r * H2_];
            E1[id * H2_ + k] = acc;
        }
    } else {
        if (t == 0) any_nz = 0;
        __syncthreads();
        int local = 0;
        for (int i = t; i < 2048; i += 256)
            if (ids32[2 * i + 1] != 0) { local = 1; break; }
        if (local) atomicOr(&any_nz, 1);
        __syncthreads();
        if (t == 0) flag[0] = (any_nz == 0) ? 1 : 0;
    }
}

// ---------------------------------------------------------------------------
// K3: MFMA main kernel (R12 structure, proven 102us). One block per task,
// 256 threads = 4 waves (wave w owns j-cols [48w,48w+48)). Per 32-K chunk:
// issue B-loads early (global, L2) -> stage h1 hi/lo into LDS (silu+split)
// -> barrier -> A via ds_read_b128 -> 36 MFMA (bf16x3) -> barrier. f64 tail.
// ONLY change vs R12: __launch_bounds__(256, 8). VGPR cap at 8 waves/EU = 64
// >= 56 actually used -> no spill possible (R13's bound-6 allocator clamp
// to 40+scratch cannot recur); 8 blocks/CU co-resident (LDS 8x15.9=127KB
// < 160) so cross-block MFMA fills this block's staging/barrier gaps.
// LDS: 5+5+1.5+1.5+0.5+2 = 15.5 KB
// ---------------------------------------------------------------------------
#define HS_ 40            // h1 LDS row stride in ushorts (80B; 2-way conflict only)
__global__ __launch_bounds__(256, 8) void k_main(const float* __restrict__ T1,
                                                 const float* __restrict__ E1,
                                                 const int*   __restrict__ ids,
                                                 const int*   __restrict__ labels,
                                                 const unsigned short* __restrict__ w2hi,
                                                 const unsigned short* __restrict__ w2lo,
                                                 const float* __restrict__ b2,
                                                 const float* __restrict__ w3,
                                                 const float* __restrict__ b3,
                                                 const float* __restrict__ cbias,
                                                 const int*   __restrict__ iflag,
                                                 float* __restrict__ out)
{
    __shared__ __align__(16) unsigned short h1hiS[C_ * HS_];  // 5 KB
    __shared__ __align__(16) unsigned short h1loS[C_ * HS_];  // 5 KB
    __shared__ __align__(16) float T1b[H2_];                  // 1.5 KB
    __shared__ float b2S[H4_], w3S[H4_];                      // 1.5 KB
    __shared__ int   ids_s[C_], lab_s[C_];                    // 0.5 KB
    __shared__ double sredS[4 * C_];                          // 2 KB

    const int b = blockIdx.x;
    const int t = threadIdx.x;
    const int l = t & 63, w = t >> 6;        // lane, wave
    const int m = l & 15, g = l >> 4;        // frag col/row-group, k-group
    const int kq0 = g * 8;                   // frag k-offset

    if (t < C_) {
        if (iflag[0]) {   // int64-world: low word of int64 elements
            ids_s[t] = (int)((const long long*)ids)[(size_t)b * C_ + t];
            lab_s[t] = (int)((const long long*)labels)[(size_t)b * C_ + t];
        } else {
            ids_s[t] = ids[b * C_ + t];
            lab_s[t] = labels[b * C_ + t];
        }
    }
    for (int k = t; k < H2_; k += 256) T1b[k] = T1[(size_t)b * H2_ + k];
    if (t < H4_) { b2S[t] = b2[t]; w3S[t] = w3[t]; }

    f32x4 acc[4][3];
    #pragma unroll
    for (int rt = 0; rt < 4; ++rt)
        #pragma unroll
        for (int jt = 0; jt < 3; ++jt) acc[rt][jt] = (f32x4){0.f, 0.f, 0.f, 0.f};

    __syncthreads();   // T1b / ids_s ready

    for (int ck = 0; ck < 12; ++ck) {
        const int kk = ck * 32;

        // --- B fragments first (independent of LDS; latency hides under staging)
        const unsigned short* gbh = w2hi + (size_t)ck * (H4_ * 32);
        const unsigned short* gbl = w2lo + (size_t)ck * (H4_ * 32);
        short8 bhi[3], blo[3];
        #pragma unroll
        for (int jt = 0; jt < 3; ++jt) {
            const int j = 48 * w + jt * 16 + m;
            bhi[jt] = *(const short8*)&gbh[j * 32 + kq0];
            blo[jt] = *(const short8*)&gbl[j * 32 + kq0];
        }

        // --- stage h1 chunk: h1[c][k] = silu(T1 + E1[id_c]), split hi/lo
        #pragma unroll
        for (int it = 0; it < 2; ++it) {
            const int i  = t + it * 256;     // 0..511
            const int c  = i >> 3;           // 0..63
            const int kq = i & 7;            // 0..7 (4 k's each)
            float4 e  = *(const float4*)&E1[(size_t)ids_s[c] * H2_ + kk + kq * 4];
            float4 tv = *(const float4*)&T1b[kk + kq * 4];
            float x0 = silu_(tv.x + e.x), x1 = silu_(tv.y + e.y);
            float x2 = silu_(tv.z + e.z), x3 = silu_(tv.w + e.w);
            unsigned short h0 = f2bf_(x0), h1v = f2bf_(x1), h2v = f2bf_(x2), h3 = f2bf_(x3);
            uint2 uh, ul;
            uh.x = (unsigned)h0 | ((unsigned)h1v << 16);
            uh.y = (unsigned)h2v | ((unsigned)h3 << 16);
            ul.x = (unsigned)f2bft_(x0 - bf2f_(h0)) | ((unsigned)f2bft_(x1 - bf2f_(h1v)) << 16);
            ul.y = (unsigned)f2bft_(x2 - bf2f_(h2v)) | ((unsigned)f2bft_(x3 - bf2f_(h3)) << 16);
            *(uint2*)&h1hiS[c * HS_ + kq * 4] = uh;
            *(uint2*)&h1loS[c * HS_ + kq * 4] = ul;
        }
        __syncthreads();

        // --- A fragments from LDS + MFMA
        short8 ahi[4], alo[4];
        #pragma unroll
        for (int rt = 0; rt < 4; ++rt) {
            ahi[rt] = *(const short8*)&h1hiS[(rt * 16 + m) * HS_ + kq0];
            alo[rt] = *(const short8*)&h1loS[(rt * 16 + m) * HS_ + kq0];
        }
        #pragma unroll
        for (int jt = 0; jt < 3; ++jt) {
            #pragma unroll
            for (int rt = 0; rt < 4; ++rt) {
                acc[rt][jt] = __builtin_amdgcn_mfma_f32_16x16x32_bf16(ahi[rt], bhi[jt], acc[rt][jt], 0, 0, 0);
                acc[rt][jt] = __builtin_amdgcn_mfma_f32_16x16x32_bf16(ahi[rt], blo[jt], acc[rt][jt], 0, 0, 0);
                acc[rt][jt] = __builtin_amdgcn_mfma_f32_16x16x32_bf16(alo[rt], bhi[jt], acc[rt][jt], 0, 0, 0);
            }
        }
        __syncthreads();   // protect h1 LDS before next chunk's staging
    }

    // --- epilogue: h2 = silu(acc + b2); p[c] = sum_j h2 * w3  (f64)
    // lane holds D[c = rt*16 + g*4 + reg][j = 48w + jt*16 + m]
    double p[4][4];
    #pragma unroll
    for (int rt = 0; rt < 4; ++rt)
        #pragma unroll
        for (int reg = 0; reg < 4; ++reg) p[rt][reg] = 0.0;

    #pragma unroll
    for (int jt = 0; jt < 3; ++jt) {
        const int j = 48 * w + jt * 16 + m;
        const float bj = b2S[j];
        const double w3j = (double)w3S[j];
        #pragma unroll
        for (int rt = 0; rt < 4; ++rt)
            #pragma unroll
            for (int reg = 0; reg < 4; ++reg)
                p[rt][reg] += (double)silu_(acc[rt][jt][reg] + bj) * w3j;
    }
    #pragma unroll
    for (int rt = 0; rt < 4; ++rt)
        #pragma unroll
        for (int reg = 0; reg < 4; ++reg) {
            double v = p[rt][reg];
            v += __shfl_xor(v, 1);
            v += __shfl_xor(v, 2);
            v += __shfl_xor(v, 4);
            v += __shfl_xor(v, 8);
            p[rt][reg] = v;
        }
    if (m == 0) {
        #pragma unroll
        for (int rt = 0; rt < 4; ++rt)
            #pragma unroll
            for (int reg = 0; reg < 4; ++reg)
                sredS[w * C_ + rt * 16 + g * 4 + reg] = p[rt][reg];
    }
    __syncthreads();

    if (t < C_) {
        const int c = t;
        double s = sredS[c] + sredS[C_ + c] + sredS[2 * C_ + c] + sredS[3 * C_ + c];
        double est = 1.0 / (1.0 + exp(-(s + (double)b3[0])));
        double rel = 1.0 / (1.0 + exp(-(est + (double)cbias[ids_s[c]])));
        out[B_ + (size_t)b * C_ + c] = (float)rel;

        // margin in f64; ties -> 0 (np argmax); (1-difficulty) factor dropped
        const int lb = lab_s[c];
        double mg = (lb == 1) ? rel : ((lb == 0) ? -rel : 0.0);
        #pragma unroll
        for (int o = 32; o > 0; o >>= 1) mg += __shfl_down(mg, o);
        if (t == 0) out[b] = (mg > 0.0) ? 1.0f : 0.0f;
    }
}

// ---------------------------------------------------------------------------
extern "C" void kernel_launch(void* const* d_in, const int* in_sizes, int n_in,
                              void* d_out, int out_size, void* d_ws, size_t ws_size,
                              hipStream_t stream)
{
    const float* te    = (const float*)d_in[0];
    const int*   ids   = (const int*)  d_in[1];
    const int*   labs  = (const int*)  d_in[2];
    const float* w1    = (const float*)d_in[3];
    const float* b1    = (const float*)d_in[4];
    const float* w2    = (const float*)d_in[5];
    const float* b2    = (const float*)d_in[6];
    const float* w3    = (const float*)d_in[7];
    const float* b3    = (const float*)d_in[8];
    const float* cbias = (const float*)d_in[14];
    const float* emb   = (const float*)d_in[13];
    float* out = (float*)d_out;

    const int expect[15] = {B_*H_, B_*C_, B_*C_, RIN_*H2_, H2_, H2_*H4_, H4_,
                            H4_, 1, H_*H2_, H2_, H2_, 1, NC_*H4_, NC_};
    if (n_in != 15) {
        k_sentinel<<<1, 1, 0, stream>>>(out, 3000.0f + (float)n_in);
        return;
    }
    for (int i = 0; i < 15; ++i) {
        if (in_sizes[i] != expect[i]) {
            k_sentinel<<<1, 1, 0, stream>>>(out, 2000.0f + 10.0f * (float)i);
            return;
        }
    }

    // ws layout: E1 f32 | T1 f32 | w1s hi/lo u16 | w2s hi/lo u16 | iflag
    const size_t nE1 = (size_t)NC_ * H2_;
    const size_t nT1 = (size_t)B_ * H2_;
    const size_t nW1 = (size_t)RIN_ * H2_;
    const size_t nW2 = (size_t)H2_ * H4_;
    const size_t need = nE1 * 4 + nT1 * 4 + nW1 * 2 * 2 + nW2 * 2 * 2 + 16;
    if (ws_size < need) {
        k_sentinel<<<1, 1, 0, stream>>>(out, 1000.0f + (float)((double)ws_size / (1024.0 * 1024.0)));
        return;
    }
    float* ws = (float*)d_ws;
    float* E1 = ws;
    float* T1 = E1 + nE1;
    unsigned short* w1hi = (unsigned short*)(T1 + nT1);
    unsigned short* w1lo = w1hi + nW1;
    unsigned short* w2hi = w1lo + nW1;
    unsigned short* w2lo = w2hi + nW2;
    int* iflag = (int*)(w2lo + nW2);

    k_w1split<<<1152, 256, 0, stream>>>(w1, w1hi, w1lo);
    k_combo<<<CB_E1E_ + 1, 256, 0, stream>>>(te, w1, w2, emb, ids,
                                             w1hi, w1lo, b1, T1,
                                             w2hi, w2lo, E1, iflag);
    k_main<<<B_, 256, 0, stream>>>(T1, E1, ids, labs, w2hi, w2lo, b2, w3, b3, cbias, iflag, out);
}

// Round 16
// 128.532 us; speedup vs baseline: 4.2949x; 4.2949x over previous
//
#include <hip/hip_runtime.h>
#include <math.h>

// Dims (fixed by the reference)
#define B_   2048
#define C_   64
#define H_   768
#define NC_  1000
#define H2_  384   // H/2
#define H4_  192   // H/4
#define RIN_ 960   // H + H/4

using short8 = __attribute__((ext_vector_type(8))) short;
using f32x4  = __attribute__((ext_vector_type(4))) float;

__device__ __forceinline__ float silu_(float x){
    float e = __expf(-x);
    return x * __fdividef(1.f, 1.f + e);
}
// round-to-nearest-even f32 -> bf16
__device__ __forceinline__ unsigned short f2bf_(float x){
    unsigned int u = __float_as_uint(x);
    u += 0x7fffu + ((u >> 16) & 1u);
    return (unsigned short)(u >> 16);
}
// truncating f32 -> bf16 (lo residuals; residual-of-residual < 2^-17)
__device__ __forceinline__ unsigned short f2bft_(float x){
    return (unsigned short)(__float_as_uint(x) >> 16);
}
__device__ __forceinline__ float bf2f_(unsigned short h){
    return __uint_as_float(((unsigned int)h) << 16);
}

__global__ void k_sentinel(float* __restrict__ out, float code){ out[0] = code; }

// ---------------------------------------------------------------------------
// K1: split w1 rows 0..767 -> chunk-major bf16 hi/lo (the only t1 dependency)
// ---------------------------------------------------------------------------
__global__ __launch_bounds__(256) void k_w1split(const float* __restrict__ w1,
                                                 unsigned short* __restrict__ w1hi,
                                                 unsigned short* __restrict__ w1lo)
{
    const int idx = blockIdx.x * 256 + threadIdx.x;
    const int k = idx / H2_, j = idx - k * H2_;
    float x = w1[idx];
    unsigned short h = f2bf_(x);
    size_t dst = (size_t)(k >> 5) * (H2_ * 32) + (size_t)j * 32 + (k & 31);
    w1hi[dst] = h;
    w1lo[dst] = f2bft_(x - bf2f_(h));
}

// ---------------------------------------------------------------------------
// K2 (combo): blockIdx dispatch over independent work
//   [0,256)     : T1 = te @ w1[:768] + b1 (MFMA bf16x3, 4 waves x 48 cols)
//   [256,544)   : split w2 (384x192) -> chunk-major bf16 hi/lo
//   [544,1544)  : E1[id] = emb[id] @ w1[768:960]
//   [1544]      : int64-vs-int32 detector on ids
// ---------------------------------------------------------------------------
#define CB_T1E_  256
#define CB_W2E_  544
#define CB_E1E_  1544
__global__ __launch_bounds__(256) void k_combo(const float* __restrict__ te,
                                               const float* __restrict__ w1,
                                               const float* __restrict__ w2,
                                               const float* __restrict__ emb,
                                               const int*   __restrict__ ids32,
                                               const unsigned short* __restrict__ w1hi,
                                               const unsigned short* __restrict__ w1lo,
                                               const float* __restrict__ b1,
                                               float* __restrict__ T1,
                                               unsigned short* __restrict__ w2hi,
                                               unsigned short* __restrict__ w2lo,
                                               float* __restrict__ E1,
                                               int* __restrict__ flag)
{
    __shared__ float er[H4_];
    __shared__ int any_nz;
    const int bb = blockIdx.x, t = threadIdx.x;

    if (bb < CB_T1E_) {
        // ---- T1 MFMA: block covers 16 task-rows x 192 cols
        const int bx = bb >> 1, by = bb & 1;
        const int b0 = bx * 16;
        const int jb = by * 192;
        const int w = t >> 6, l = t & 63;
        const int m = l & 15, g = l >> 4;
        const int row = b0 + m;

        f32x4 acc[3];
        #pragma unroll
        for (int jt = 0; jt < 3; ++jt) acc[jt] = (f32x4){0.f, 0.f, 0.f, 0.f};

        for (int ck = 0; ck < 24; ++ck) {
            const int kk = ck * 32;
            const float* pa = te + (size_t)row * H_ + kk + g * 8;
            float4 a0 = *(const float4*)pa;
            float4 a1 = *(const float4*)(pa + 4);
            float av[8] = {a0.x, a0.y, a0.z, a0.w, a1.x, a1.y, a1.z, a1.w};
            short8 ahi, alo;
            #pragma unroll
            for (int i = 0; i < 8; ++i) {
                unsigned short h = f2bf_(av[i]);
                ahi[i] = (short)h;
                alo[i] = (short)f2bft_(av[i] - bf2f_(h));
            }
            #pragma unroll
            for (int jt = 0; jt < 3; ++jt) {
                const int j = jb + w * 48 + jt * 16 + m;
                const size_t o = (size_t)ck * (H2_ * 32) + (size_t)j * 32 + g * 8;
                short8 bhi = *(const short8*)&w1hi[o];
                short8 blo = *(const short8*)&w1lo[o];
                acc[jt] = __builtin_amdgcn_mfma_f32_16x16x32_bf16(ahi, bhi, acc[jt], 0, 0, 0);
                acc[jt] = __builtin_amdgcn_mfma_f32_16x16x32_bf16(ahi, blo, acc[jt], 0, 0, 0);
                acc[jt] = __builtin_amdgcn_mfma_f32_16x16x32_bf16(alo, bhi, acc[jt], 0, 0, 0);
            }
        }
        #pragma unroll
        for (int jt = 0; jt < 3; ++jt) {
            const int j = jb + w * 48 + jt * 16 + m;
            const float bj = b1[j];
            #pragma unroll
            for (int reg = 0; reg < 4; ++reg)
                T1[(size_t)(b0 + g * 4 + reg) * H2_ + j] = acc[jt][reg] + bj;
        }
    } else if (bb < CB_W2E_) {
        const int idx = (bb - CB_T1E_) * 256 + t;      // < 384*192 exactly
        const int k = idx / H4_, j = idx - k * H4_;
        float x = w2[idx];
        unsigned short h = f2bf_(x);
        size_t dst = (size_t)(k >> 5) * (H4_ * 32) + (size_t)j * 32 + (k & 31);
        w2hi[dst] = h;
        w2lo[dst] = f2bft_(x - bf2f_(h));
    } else if (bb < CB_E1E_) {
        const int id = bb - CB_W2E_;
        if (t < H4_) er[t] = emb[id * H4_ + t];
        __syncthreads();
        for (int k = t; k < H2_; k += 256) {
            float acc = 0.f;
            const float* wc = w1 + (size_t)H_ * H2_ + k;
            #pragma unroll 8
            for (int r = 0; r < H4_; ++r) acc += er[r] * wc[(size_t)r * H2_];
            E1[id * H2_ + k] = acc;
        }
    } else {
        if (t == 0) any_nz = 0;
        __syncthreads();
        int local = 0;
        for (int i = t; i < 2048; i += 256)
            if (ids32[2 * i + 1] != 0) { local = 1; break; }
        if (local) atomicOr(&any_nz, 1);
        __syncthreads();
        if (t == 0) flag[0] = (any_nz == 0) ? 1 : 0;
    }
}

// ---------------------------------------------------------------------------
// K3: MFMA main kernel (R12 structure, proven 102us). One block per task,
// 256 threads = 4 waves (wave w owns j-cols [48w,48w+48)). Per 32-K chunk:
// issue B-loads early (global, L2) -> stage h1 hi/lo into LDS (silu+split)
// -> barrier -> A via ds_read_b128 -> 36 MFMA (bf16x3) -> barrier. f64 tail.
// ONLY change vs R12: __launch_bounds__(256) with NO min-waves arg.
// The allocator is unconstrained (natural ~56 VGPR, spill-impossible);
// HW residency is then set by actual usage: 512/56 -> 8 waves/SIMD possible,
// LDS 15.5KB -> 10 blocks/CU possible. (Bound-N experiments R13/R15 proved
// the allocator clamps+spills when the bound binds: 6->40VGPR, 8->32VGPR.)
// LDS: 5+5+1.5+1.5+0.5+2 = 15.5 KB
// ---------------------------------------------------------------------------
#define HS_ 40            // h1 LDS row stride in ushorts (80B; 2-way conflict only)
__global__ __launch_bounds__(256) void k_main(const float* __restrict__ T1,
                                              const float* __restrict__ E1,
                                              const int*   __restrict__ ids,
                                              const int*   __restrict__ labels,
                                              const unsigned short* __restrict__ w2hi,
                                              const unsigned short* __restrict__ w2lo,
                                              const float* __restrict__ b2,
                                              const float* __restrict__ w3,
                                              const float* __restrict__ b3,
                                              const float* __restrict__ cbias,
                                              const int*   __restrict__ iflag,
                                              float* __restrict__ out)
{
    __shared__ __align__(16) unsigned short h1hiS[C_ * HS_];  // 5 KB
    __shared__ __align__(16) unsigned short h1loS[C_ * HS_];  // 5 KB
    __shared__ __align__(16) float T1b[H2_];                  // 1.5 KB
    __shared__ float b2S[H4_], w3S[H4_];                      // 1.5 KB
    __shared__ int   ids_s[C_], lab_s[C_];                    // 0.5 KB
    __shared__ double sredS[4 * C_];                          // 2 KB

    const int b = blockIdx.x;
    const int t = threadIdx.x;
    const int l = t & 63, w = t >> 6;        // lane, wave
    const int m = l & 15, g = l >> 4;        // frag col/row-group, k-group
    const int kq0 = g * 8;                   // frag k-offset

    if (t < C_) {
        if (iflag[0]) {   // int64-world: low word of int64 elements
            ids_s[t] = (int)((const long long*)ids)[(size_t)b * C_ + t];
            lab_s[t] = (int)((const long long*)labels)[(size_t)b * C_ + t];
        } else {
            ids_s[t] = ids[b * C_ + t];
            lab_s[t] = labels[b * C_ + t];
        }
    }
    for (int k = t; k < H2_; k += 256) T1b[k] = T1[(size_t)b * H2_ + k];
    if (t < H4_) { b2S[t] = b2[t]; w3S[t] = w3[t]; }

    f32x4 acc[4][3];
    #pragma unroll
    for (int rt = 0; rt < 4; ++rt)
        #pragma unroll
        for (int jt = 0; jt < 3; ++jt) acc[rt][jt] = (f32x4){0.f, 0.f, 0.f, 0.f};

    __syncthreads();   // T1b / ids_s ready

    for (int ck = 0; ck < 12; ++ck) {
        const int kk = ck * 32;

        // --- B fragments first (independent of LDS; latency hides under staging)
        const unsigned short* gbh = w2hi + (size_t)ck * (H4_ * 32);
        const unsigned short* gbl = w2lo + (size_t)ck * (H4_ * 32);
        short8 bhi[3], blo[3];
        #pragma unroll
        for (int jt = 0; jt < 3; ++jt) {
            const int j = 48 * w + jt * 16 + m;
            bhi[jt] = *(const short8*)&gbh[j * 32 + kq0];
            blo[jt] = *(const short8*)&gbl[j * 32 + kq0];
        }

        // --- stage h1 chunk: h1[c][k] = silu(T1 + E1[id_c]), split hi/lo
        #pragma unroll
        for (int it = 0; it < 2; ++it) {
            const int i  = t + it * 256;     // 0..511
            const int c  = i >> 3;           // 0..63
            const int kq = i & 7;            // 0..7 (4 k's each)
            float4 e  = *(const float4*)&E1[(size_t)ids_s[c] * H2_ + kk + kq * 4];
            float4 tv = *(const float4*)&T1b[kk + kq * 4];
            float x0 = silu_(tv.x + e.x), x1 = silu_(tv.y + e.y);
            float x2 = silu_(tv.z + e.z), x3 = silu_(tv.w + e.w);
            unsigned short h0 = f2bf_(x0), h1v = f2bf_(x1), h2v = f2bf_(x2), h3 = f2bf_(x3);
            uint2 uh, ul;
            uh.x = (unsigned)h0 | ((unsigned)h1v << 16);
            uh.y = (unsigned)h2v | ((unsigned)h3 << 16);
            ul.x = (unsigned)f2bft_(x0 - bf2f_(h0)) | ((unsigned)f2bft_(x1 - bf2f_(h1v)) << 16);
            ul.y = (unsigned)f2bft_(x2 - bf2f_(h2v)) | ((unsigned)f2bft_(x3 - bf2f_(h3)) << 16);
            *(uint2*)&h1hiS[c * HS_ + kq * 4] = uh;
            *(uint2*)&h1loS[c * HS_ + kq * 4] = ul;
        }
        __syncthreads();

        // --- A fragments from LDS + MFMA
        short8 ahi[4], alo[4];
        #pragma unroll
        for (int rt = 0; rt < 4; ++rt) {
            ahi[rt] = *(const short8*)&h1hiS[(rt * 16 + m) * HS_ + kq0];
            alo[rt] = *(const short8*)&h1loS[(rt * 16 + m) * HS_ + kq0];
        }
        #pragma unroll
        for (int jt = 0; jt < 3; ++jt) {
            #pragma unroll
            for (int rt = 0; rt < 4; ++rt) {
                acc[rt][jt] = __builtin_amdgcn_mfma_f32_16x16x32_bf16(ahi[rt], bhi[jt], acc[rt][jt], 0, 0, 0);
                acc[rt][jt] = __builtin_amdgcn_mfma_f32_16x16x32_bf16(ahi[rt], blo[jt], acc[rt][jt], 0, 0, 0);
                acc[rt][jt] = __builtin_amdgcn_mfma_f32_16x16x32_bf16(alo[rt], bhi[jt], acc[rt][jt], 0, 0, 0);
            }
        }
        __syncthreads();   // protect h1 LDS before next chunk's staging
    }

    // --- epilogue: h2 = silu(acc + b2); p[c] = sum_j h2 * w3  (f64)
    // lane holds D[c = rt*16 + g*4 + reg][j = 48w + jt*16 + m]
    double p[4][4];
    #pragma unroll
    for (int rt = 0; rt < 4; ++rt)
        #pragma unroll
        for (int reg = 0; reg < 4; ++reg) p[rt][reg] = 0.0;

    #pragma unroll
    for (int jt = 0; jt < 3; ++jt) {
        const int j = 48 * w + jt * 16 + m;
        const float bj = b2S[j];
        const double w3j = (double)w3S[j];
        #pragma unroll
        for (int rt = 0; rt < 4; ++rt)
            #pragma unroll
            for (int reg = 0; reg < 4; ++reg)
                p[rt][reg] += (double)silu_(acc[rt][jt][reg] + bj) * w3j;
    }
    #pragma unroll
    for (int rt = 0; rt < 4; ++rt)
        #pragma unroll
        for (int reg = 0; reg < 4; ++reg) {
            double v = p[rt][reg];
            v += __shfl_xor(v, 1);
            v += __shfl_xor(v, 2);
            v += __shfl_xor(v, 4);
            v += __shfl_xor(v, 8);
            p[rt][reg] = v;
        }
    if (m == 0) {
        #pragma unroll
        for (int rt = 0; rt < 4; ++rt)
            #pragma unroll
            for (int reg = 0; reg < 4; ++reg)
                sredS[w * C_ + rt * 16 + g * 4 + reg] = p[rt][reg];
    }
    __syncthreads();

    if (t < C_) {
        const int c = t;
        double s = sredS[c] + sredS[C_ + c] + sredS[2 * C_ + c] + sredS[3 * C_ + c];
        double est = 1.0 / (1.0 + exp(-(s + (double)b3[0])));
        double rel = 1.0 / (1.0 + exp(-(est + (double)cbias[ids_s[c]])));
        out[B_ + (size_t)b * C_ + c] = (float)rel;

        // margin in f64; ties -> 0 (np argmax); (1-difficulty) factor dropped
        const int lb = lab_s[c];
        double mg = (lb == 1) ? rel : ((lb == 0) ? -rel : 0.0);
        #pragma unroll
        for (int o = 32; o > 0; o >>= 1) mg += __shfl_down(mg, o);
        if (t == 0) out[b] = (mg > 0.0) ? 1.0f : 0.0f;
    }
}

// ---------------------------------------------------------------------------
extern "C" void kernel_launch(void* const* d_in, const int* in_sizes, int n_in,
                              void* d_out, int out_size, void* d_ws, size_t ws_size,
                              hipStream_t stream)
{
    const float* te    = (const float*)d_in[0];
    const int*   ids   = (const int*)  d_in[1];
    const int*   labs  = (const int*)  d_in[2];
    const float* w1    = (const float*)d_in[3];
    const float* b1    = (const float*)d_in[4];
    const float* w2    = (const float*)d_in[5];
    const float* b2    = (const float*)d_in[6];
    const float* w3    = (const float*)d_in[7];
    const float* b3    = (const float*)d_in[8];
    const float* cbias = (const float*)d_in[14];
    const float* emb   = (const float*)d_in[13];
    float* out = (float*)d_out;

    const int expect[15] = {B_*H_, B_*C_, B_*C_, RIN_*H2_, H2_, H2_*H4_, H4_,
                            H4_, 1, H_*H2_, H2_, H2_, 1, NC_*H4_, NC_};
    if (n_in != 15) {
        k_sentinel<<<1, 1, 0, stream>>>(out, 3000.0f + (float)n_in);
        return;
    }
    for (int i = 0; i < 15; ++i) {
        if (in_sizes[i] != expect[i]) {
            k_sentinel<<<1, 1, 0, stream>>>(out, 2000.0f + 10.0f * (float)i);
            return;
        }
    }

    // ws layout: E1 f32 | T1 f32 | w1s hi/lo u16 | w2s hi/lo u16 | iflag
    const size_t nE1 = (size_t)NC_ * H2_;
    const size_t nT1 = (size_t)B_ * H2_;
    const size_t nW1 = (size_t)RIN_ * H2_;
    const size_t nW2 = (size_t)H2_ * H4_;
    const size_t need = nE1 * 4 + nT1 * 4 + nW1 * 2 * 2 + nW2 * 2 * 2 + 16;
    if (ws_size < need) {
        k_sentinel<<<1, 1, 0, stream>>>(out, 1000.0f + (float)((double)ws_size / (1024.0 * 1024.0)));
        return;
    }
    float* ws = (float*)d_ws;
    float* E1 = ws;
    float* T1 = E1 + nE1;
    unsigned short* w1hi = (unsigned short*)(T1 + nT1);
    unsigned short* w1lo = w1hi + nW1;
    unsigned short* w2hi = w1lo + nW1;
    unsigned short* w2lo = w2hi + nW2;
    int* iflag = (int*)(w2lo + nW2);

    k_w1split<<<1152, 256, 0, stream>>>(w1, w1hi, w1lo);
    k_combo<<<CB_E1E_ + 1, 256, 0, stream>>>(te, w1, w2, emb, ids,
                                             w1hi, w1lo, b1, T1,
                                             w2hi, w2lo, E1, iflag);
    k_main<<<B_, 256, 0, stream>>>(T1, E1, ids, labs, w2hi, w2lo, b2, w3, b3, cbias, iflag, out);
}

// Round 17
// 121.127 us; speedup vs baseline: 4.5574x; 1.0611x over previous
//
#include <hip/hip_runtime.h>
#include <math.h>

// Dims (fixed by the reference)
#define B_   2048
#define C_   64
#define H_   768
#define NC_  1000
#define H2_  384   // H/2
#define H4_  192   // H/4
#define RIN_ 960   // H + H/4

using short8 = __attribute__((ext_vector_type(8))) short;
using f32x4  = __attribute__((ext_vector_type(4))) float;

__device__ __forceinline__ float silu_(float x){
    float e = __expf(-x);
    return x * __fdividef(1.f, 1.f + e);
}
// round-to-nearest-even f32 -> bf16
__device__ __forceinline__ unsigned short f2bf_(float x){
    unsigned int u = __float_as_uint(x);
    u += 0x7fffu + ((u >> 16) & 1u);
    return (unsigned short)(u >> 16);
}
// truncating f32 -> bf16 (hi and lo residuals; residual-of-residual < 2^-17)
__device__ __forceinline__ unsigned short f2bft_(float x){
    return (unsigned short)(__float_as_uint(x) >> 16);
}
__device__ __forceinline__ float bf2f_(unsigned short h){
    return __uint_as_float(((unsigned int)h) << 16);
}

__global__ void k_sentinel(float* __restrict__ out, float code){ out[0] = code; }

// ---------------------------------------------------------------------------
// K1: split w1 rows 0..767 -> chunk-major bf16 hi/lo (the only t1 dependency)
// ---------------------------------------------------------------------------
__global__ __launch_bounds__(256) void k_w1split(const float* __restrict__ w1,
                                                 unsigned short* __restrict__ w1hi,
                                                 unsigned short* __restrict__ w1lo)
{
    const int idx = blockIdx.x * 256 + threadIdx.x;
    const int k = idx / H2_, j = idx - k * H2_;
    float x = w1[idx];
    unsigned short h = f2bf_(x);
    size_t dst = (size_t)(k >> 5) * (H2_ * 32) + (size_t)j * 32 + (k & 31);
    w1hi[dst] = h;
    w1lo[dst] = f2bft_(x - bf2f_(h));
}

// ---------------------------------------------------------------------------
// K2 (combo): blockIdx dispatch over independent work
//   [0,256)     : T1 = te @ w1[:768] + b1 (MFMA bf16x3, 4 waves x 48 cols)
//   [256,544)   : split w2 (384x192) -> chunk-major bf16 hi/lo
//   [544,1544)  : E1[id] = emb[id] @ w1[768:960]
//   [1544]      : int64-vs-int32 detector on ids
// ---------------------------------------------------------------------------
#define CB_T1E_  256
#define CB_W2E_  544
#define CB_E1E_  1544
__global__ __launch_bounds__(256) void k_combo(const float* __restrict__ te,
                                               const float* __restrict__ w1,
                                               const float* __restrict__ w2,
                                               const float* __restrict__ emb,
                                               const int*   __restrict__ ids32,
                                               const unsigned short* __restrict__ w1hi,
                                               const unsigned short* __restrict__ w1lo,
                                               const float* __restrict__ b1,
                                               float* __restrict__ T1,
                                               unsigned short* __restrict__ w2hi,
                                               unsigned short* __restrict__ w2lo,
                                               float* __restrict__ E1,
                                               int* __restrict__ flag)
{
    __shared__ float er[H4_];
    __shared__ int any_nz;
    const int bb = blockIdx.x, t = threadIdx.x;

    if (bb < CB_T1E_) {
        // ---- T1 MFMA: block covers 16 task-rows x 192 cols
        const int bx = bb >> 1, by = bb & 1;
        const int b0 = bx * 16;
        const int jb = by * 192;
        const int w = t >> 6, l = t & 63;
        const int m = l & 15, g = l >> 4;
        const int row = b0 + m;

        f32x4 acc[3];
        #pragma unroll
        for (int jt = 0; jt < 3; ++jt) acc[jt] = (f32x4){0.f, 0.f, 0.f, 0.f};

        for (int ck = 0; ck < 24; ++ck) {
            const int kk = ck * 32;
            const float* pa = te + (size_t)row * H_ + kk + g * 8;
            float4 a0 = *(const float4*)pa;
            float4 a1 = *(const float4*)(pa + 4);
            float av[8] = {a0.x, a0.y, a0.z, a0.w, a1.x, a1.y, a1.z, a1.w};
            short8 ahi, alo;
            #pragma unroll
            for (int i = 0; i < 8; ++i) {
                unsigned short h = f2bf_(av[i]);
                ahi[i] = (short)h;
                alo[i] = (short)f2bft_(av[i] - bf2f_(h));
            }
            #pragma unroll
            for (int jt = 0; jt < 3; ++jt) {
                const int j = jb + w * 48 + jt * 16 + m;
                const size_t o = (size_t)ck * (H2_ * 32) + (size_t)j * 32 + g * 8;
                short8 bhi = *(const short8*)&w1hi[o];
                short8 blo = *(const short8*)&w1lo[o];
                acc[jt] = __builtin_amdgcn_mfma_f32_16x16x32_bf16(ahi, bhi, acc[jt], 0, 0, 0);
                acc[jt] = __builtin_amdgcn_mfma_f32_16x16x32_bf16(ahi, blo, acc[jt], 0, 0, 0);
                acc[jt] = __builtin_amdgcn_mfma_f32_16x16x32_bf16(alo, bhi, acc[jt], 0, 0, 0);
            }
        }
        #pragma unroll
        for (int jt = 0; jt < 3; ++jt) {
            const int j = jb + w * 48 + jt * 16 + m;
            const float bj = b1[j];
            #pragma unroll
            for (int reg = 0; reg < 4; ++reg)
                T1[(size_t)(b0 + g * 4 + reg) * H2_ + j] = acc[jt][reg] + bj;
        }
    } else if (bb < CB_W2E_) {
        const int idx = (bb - CB_T1E_) * 256 + t;      // < 384*192 exactly
        const int k = idx / H4_, j = idx - k * H4_;
        float x = w2[idx];
        unsigned short h = f2bf_(x);
        size_t dst = (size_t)(k >> 5) * (H4_ * 32) + (size_t)j * 32 + (k & 31);
        w2hi[dst] = h;
        w2lo[dst] = f2bft_(x - bf2f_(h));
    } else if (bb < CB_E1E_) {
        const int id = bb - CB_W2E_;
        if (t < H4_) er[t] = emb[id * H4_ + t];
        __syncthreads();
        for (int k = t; k < H2_; k += 256) {
            float acc = 0.f;
            const float* wc = w1 + (size_t)H_ * H2_ + k;
            #pragma unroll 8
            for (int r = 0; r < H4_; ++r) acc += er[r] * wc[(size_t)r * H2_];
            E1[id * H2_ + k] = acc;
        }
    } else {
        if (t == 0) any_nz = 0;
        __syncthreads();
        int local = 0;
        for (int i = t; i < 2048; i += 256)
            if (ids32[2 * i + 1] != 0) { local = 1; break; }
        if (local) atomicOr(&any_nz, 1);
        __syncthreads();
        if (t == 0) flag[0] = (any_nz == 0) ? 1 : 0;
    }
}

// ---------------------------------------------------------------------------
// K3: MFMA main kernel (R12 structure + convoy-breaking chunk stagger).
// One block per task, 256 threads = 4 waves (wave w owns j-cols [48w,48w+48)).
// Per 32-K chunk: B-loads early (global, L2) -> stage h1 hi/lo into LDS
// (silu + TRUNC split, ~20% less staging VALU; error class unchanged 2^-17)
// -> barrier -> A via ds_read_b128 -> 36 MFMA (bf16x3) -> barrier. f64 tail.
// Chunk order rotated by (blockIdx % 12) so co-resident blocks are at
// different phases (one stages while another MFMAs) instead of convoying.
// __launch_bounds__(256,4): proven optimum (ledger: 4->56VGPR/102us,
// none->84/107, 6->40+spill/165, 8->32+spill/519).
// LDS: 5+5+1.5+1.5+0.5+2 = 15.5 KB
// ---------------------------------------------------------------------------
#define HS_ 40            // h1 LDS row stride in ushorts (80B; 2-way conflict only)
__global__ __launch_bounds__(256, 4) void k_main(const float* __restrict__ T1,
                                                 const float* __restrict__ E1,
                                                 const int*   __restrict__ ids,
                                                 const int*   __restrict__ labels,
                                                 const unsigned short* __restrict__ w2hi,
                                                 const unsigned short* __restrict__ w2lo,
                                                 const float* __restrict__ b2,
                                                 const float* __restrict__ w3,
                                                 const float* __restrict__ b3,
                                                 const float* __restrict__ cbias,
                                                 const int*   __restrict__ iflag,
                                                 float* __restrict__ out)
{
    __shared__ __align__(16) unsigned short h1hiS[C_ * HS_];  // 5 KB
    __shared__ __align__(16) unsigned short h1loS[C_ * HS_];  // 5 KB
    __shared__ __align__(16) float T1b[H2_];                  // 1.5 KB
    __shared__ float b2S[H4_], w3S[H4_];                      // 1.5 KB
    __shared__ int   ids_s[C_], lab_s[C_];                    // 0.5 KB
    __shared__ double sredS[4 * C_];                          // 2 KB

    const int b = blockIdx.x;
    const int t = threadIdx.x;
    const int l = t & 63, w = t >> 6;        // lane, wave
    const int m = l & 15, g = l >> 4;        // frag col/row-group, k-group
    const int kq0 = g * 8;                   // frag k-offset

    if (t < C_) {
        if (iflag[0]) {   // int64-world: low word of int64 elements
            ids_s[t] = (int)((const long long*)ids)[(size_t)b * C_ + t];
            lab_s[t] = (int)((const long long*)labels)[(size_t)b * C_ + t];
        } else {
            ids_s[t] = ids[b * C_ + t];
            lab_s[t] = labels[b * C_ + t];
        }
    }
    for (int k = t; k < H2_; k += 256) T1b[k] = T1[(size_t)b * H2_ + k];
    if (t < H4_) { b2S[t] = b2[t]; w3S[t] = w3[t]; }

    f32x4 acc[4][3];
    #pragma unroll
    for (int rt = 0; rt < 4; ++rt)
        #pragma unroll
        for (int jt = 0; jt < 3; ++jt) acc[rt][jt] = (f32x4){0.f, 0.f, 0.f, 0.f};

    __syncthreads();   // T1b / ids_s ready

    const int ck0 = b % 12;    // phase stagger: co-resident blocks desynced
    for (int ci = 0; ci < 12; ++ci) {
        int ck = ck0 + ci;
        if (ck >= 12) ck -= 12;
        const int kk = ck * 32;

        // --- B fragments first (independent of LDS; latency hides under staging)
        const unsigned short* gbh = w2hi + (size_t)ck * (H4_ * 32);
        const unsigned short* gbl = w2lo + (size_t)ck * (H4_ * 32);
        short8 bhi[3], blo[3];
        #pragma unroll
        for (int jt = 0; jt < 3; ++jt) {
            const int j = 48 * w + jt * 16 + m;
            bhi[jt] = *(const short8*)&gbh[j * 32 + kq0];
            blo[jt] = *(const short8*)&gbl[j * 32 + kq0];
        }

        // --- stage h1 chunk: h1[c][k] = silu(T1 + E1[id_c]), TRUNC hi/lo split
        #pragma unroll
        for (int it = 0; it < 2; ++it) {
            const int i  = t + it * 256;     // 0..511
            const int c  = i >> 3;           // 0..63
            const int kq = i & 7;            // 0..7 (4 k's each)
            float4 e  = *(const float4*)&E1[(size_t)ids_s[c] * H2_ + kk + kq * 4];
            float4 tv = *(const float4*)&T1b[kk + kq * 4];
            float x0 = silu_(tv.x + e.x), x1 = silu_(tv.y + e.y);
            float x2 = silu_(tv.z + e.z), x3 = silu_(tv.w + e.w);
            unsigned short h0 = f2bft_(x0), h1v = f2bft_(x1), h2v = f2bft_(x2), h3 = f2bft_(x3);
            uint2 uh, ul;
            uh.x = (unsigned)h0 | ((unsigned)h1v << 16);
            uh.y = (unsigned)h2v | ((unsigned)h3 << 16);
            ul.x = (unsigned)f2bft_(x0 - bf2f_(h0)) | ((unsigned)f2bft_(x1 - bf2f_(h1v)) << 16);
            ul.y = (unsigned)f2bft_(x2 - bf2f_(h2v)) | ((unsigned)f2bft_(x3 - bf2f_(h3)) << 16);
            *(uint2*)&h1hiS[c * HS_ + kq * 4] = uh;
            *(uint2*)&h1loS[c * HS_ + kq * 4] = ul;
        }
        __syncthreads();

        // --- A fragments from LDS + MFMA
        short8 ahi[4], alo[4];
        #pragma unroll
        for (int rt = 0; rt < 4; ++rt) {
            ahi[rt] = *(const short8*)&h1hiS[(rt * 16 + m) * HS_ + kq0];
            alo[rt] = *(const short8*)&h1loS[(rt * 16 + m) * HS_ + kq0];
        }
        #pragma unroll
        for (int jt = 0; jt < 3; ++jt) {
            #pragma unroll
            for (int rt = 0; rt < 4; ++rt) {
                acc[rt][jt] = __builtin_amdgcn_mfma_f32_16x16x32_bf16(ahi[rt], bhi[jt], acc[rt][jt], 0, 0, 0);
                acc[rt][jt] = __builtin_amdgcn_mfma_f32_16x16x32_bf16(ahi[rt], blo[jt], acc[rt][jt], 0, 0, 0);
                acc[rt][jt] = __builtin_amdgcn_mfma_f32_16x16x32_bf16(alo[rt], bhi[jt], acc[rt][jt], 0, 0, 0);
            }
        }
        __syncthreads();   // protect h1 LDS before next chunk's staging
    }

    // --- epilogue: h2 = silu(acc + b2); p[c] = sum_j h2 * w3  (f64)
    // lane holds D[c = rt*16 + g*4 + reg][j = 48w + jt*16 + m]
    double p[4][4];
    #pragma unroll
    for (int rt = 0; rt < 4; ++rt)
        #pragma unroll
        for (int reg = 0; reg < 4; ++reg) p[rt][reg] = 0.0;

    #pragma unroll
    for (int jt = 0; jt < 3; ++jt) {
        const int j = 48 * w + jt * 16 + m;
        const float bj = b2S[j];
        const double w3j = (double)w3S[j];
        #pragma unroll
        for (int rt = 0; rt < 4; ++rt)
            #pragma unroll
            for (int reg = 0; reg < 4; ++reg)
                p[rt][reg] += (double)silu_(acc[rt][jt][reg] + bj) * w3j;
    }
    #pragma unroll
    for (int rt = 0; rt < 4; ++rt)
        #pragma unroll
        for (int reg = 0; reg < 4; ++reg) {
            double v = p[rt][reg];
            v += __shfl_xor(v, 1);
            v += __shfl_xor(v, 2);
            v += __shfl_xor(v, 4);
            v += __shfl_xor(v, 8);
            p[rt][reg] = v;
        }
    if (m == 0) {
        #pragma unroll
        for (int rt = 0; rt < 4; ++rt)
            #pragma unroll
            for (int reg = 0; reg < 4; ++reg)
                sredS[w * C_ + rt * 16 + g * 4 + reg] = p[rt][reg];
    }
    __syncthreads();

    if (t < C_) {
        const int c = t;
        double s = sredS[c] + sredS[C_ + c] + sredS[2 * C_ + c] + sredS[3 * C_ + c];
        double est = 1.0 / (1.0 + exp(-(s + (double)b3[0])));
        double rel = 1.0 / (1.0 + exp(-(est + (double)cbias[ids_s[c]])));
        out[B_ + (size_t)b * C_ + c] = (float)rel;

        // margin in f64; ties -> 0 (np argmax); (1-difficulty) factor dropped
        const int lb = lab_s[c];
        double mg = (lb == 1) ? rel : ((lb == 0) ? -rel : 0.0);
        #pragma unroll
        for (int o = 32; o > 0; o >>= 1) mg += __shfl_down(mg, o);
        if (t == 0) out[b] = (mg > 0.0) ? 1.0f : 0.0f;
    }
}

// ---------------------------------------------------------------------------
extern "C" void kernel_launch(void* const* d_in, const int* in_sizes, int n_in,
                              void* d_out, int out_size, void* d_ws, size_t ws_size,
                              hipStream_t stream)
{
    const float* te    = (const float*)d_in[0];
    const int*   ids   = (const int*)  d_in[1];
    const int*   labs  = (const int*)  d_in[2];
    const float* w1    = (const float*)d_in[3];
    const float* b1    = (const float*)d_in[4];
    const float* w2    = (const float*)d_in[5];
    const float* b2    = (const float*)d_in[6];
    const float* w3    = (const float*)d_in[7];
    const float* b3    = (const float*)d_in[8];
    const float* cbias = (const float*)d_in[14];
    const float* emb   = (const float*)d_in[13];
    float* out = (float*)d_out;

    const int expect[15] = {B_*H_, B_*C_, B_*C_, RIN_*H2_, H2_, H2_*H4_, H4_,
                            H4_, 1, H_*H2_, H2_, H2_, 1, NC_*H4_, NC_};
    if (n_in != 15) {
        k_sentinel<<<1, 1, 0, stream>>>(out, 3000.0f + (float)n_in);
        return;
    }
    for (int i = 0; i < 15; ++i) {
        if (in_sizes[i] != expect[i]) {
            k_sentinel<<<1, 1, 0, stream>>>(out, 2000.0f + 10.0f * (float)i);
            return;
        }
    }

    // ws layout: E1 f32 | T1 f32 | w1s hi/lo u16 | w2s hi/lo u16 | iflag
    const size_t nE1 = (size_t)NC_ * H2_;
    const size_t nT1 = (size_t)B_ * H2_;
    const size_t nW1 = (size_t)RIN_ * H2_;
    const size_t nW2 = (size_t)H2_ * H4_;
    const size_t need = nE1 * 4 + nT1 * 4 + nW1 * 2 * 2 + nW2 * 2 * 2 + 16;
    if (ws_size < need) {
        k_sentinel<<<1, 1, 0, stream>>>(out, 1000.0f + (float)((double)ws_size / (1024.0 * 1024.0)));
        return;
    }
    float* ws = (float*)d_ws;
    float* E1 = ws;
    float* T1 = E1 + nE1;
    unsigned short* w1hi = (unsigned short*)(T1 + nT1);
    unsigned short* w1lo = w1hi + nW1;
    unsigned short* w2hi = w1lo + nW1;
    unsigned short* w2lo = w2hi + nW2;
    int* iflag = (int*)(w2lo + nW2);

    k_w1split<<<1152, 256, 0, stream>>>(w1, w1hi, w1lo);
    k_combo<<<CB_E1E_ + 1, 256, 0, stream>>>(te, w1, w2, emb, ids,
                                             w1hi, w1lo, b1, T1,
                                             w2hi, w2lo, E1, iflag);
    k_main<<<B_, 256, 0, stream>>>(T1, E1, ids, labs, w2hi, w2lo, b2, w3, b3, cbias, iflag, out);
}